// Round 14
// baseline (138.079 us; speedup 1.0000x reference)
//
#include <hip/hip_runtime.h>
#include <hip/hip_bf16.h>
#include <math.h>

#define Bb 2
#define Tt 2048
#define Cc 1024
#define Hh 16
#define HDd 64
#define QSCALE 0.18033688011112042f   // 0.125 * log2(e): folds softmax scale + exp->exp2

typedef __attribute__((ext_vector_type(8))) short short8;
typedef __attribute__((ext_vector_type(4))) short short4v;
typedef __attribute__((ext_vector_type(4))) float f32x4;

#if defined(__has_builtin)
#if __has_builtin(__builtin_amdgcn_global_load_lds)
#define USE_GLL 1
#endif
#endif
#define AS_GLOBAL __attribute__((address_space(1)))
#define AS_LDS    __attribute__((address_space(3)))

__device__ __forceinline__ float bf2f(unsigned short u){
  union { unsigned int i; float f; } v; v.i = ((unsigned int)u)<<16; return v.f;
}
__device__ __forceinline__ unsigned short f2bf(float f){
  union { float f; unsigned int i; } v; v.f = f;
  unsigned int x = v.i;
  return (unsigned short)((x + 0x7fffu + ((x>>16)&1u)) >> 16);
}
__device__ __forceinline__ unsigned int cvtpk_bf16(float lo, float hi){
  unsigned int r;
  asm("v_cvt_pk_bf16_f32 %0, %1, %2" : "=v"(r) : "v"(lo), "v"(hi));
  return r;
}
__device__ __forceinline__ float exp2fast(float x){
  float r; asm("v_exp_f32 %0, %1" : "=v"(r) : "v"(x)); return r;
}
__device__ __forceinline__ f32x4 mfma16(short4v a, short4v b, f32x4 c){
#if defined(__has_builtin)
#if __has_builtin(__builtin_amdgcn_mfma_f32_16x16x16_bf16)
  return __builtin_amdgcn_mfma_f32_16x16x16_bf16(a, b, c, 0, 0, 0);
#elif __has_builtin(__builtin_amdgcn_mfma_f32_16x16x16bf16_1k)
  return __builtin_amdgcn_mfma_f32_16x16x16bf16_1k(a, b, c, 0, 0, 0);
#else
  asm("v_mfma_f32_16x16x16_bf16 %0, %1, %2, %3" : "=v"(c) : "v"(a), "v"(b), "0"(c));
  return c;
#endif
#else
  asm("v_mfma_f32_16x16x16_bf16 %0, %1, %2, %3" : "=v"(c) : "v"(a), "v"(b), "0"(c));
  return c;
#endif
}

// ---------------- fp32 -> bf16 convert (8 elems/thread, 16B stores) ----------------
__global__ __launch_bounds__(256) void k_f2b(const float* __restrict__ in,
                                             unsigned short* __restrict__ out, int n){
  int i = (blockIdx.x*256 + threadIdx.x)*8;
  if (i >= n) return;
  float4 v0 = *(const float4*)(in + i);
  float4 v1 = *(const float4*)(in + i + 4);
  union { unsigned int u[4]; int4 v; } pk;
  pk.u[0] = cvtpk_bf16(v0.x, v0.y);
  pk.u[1] = cvtpk_bf16(v0.z, v0.w);
  pk.u[2] = cvtpk_bf16(v1.x, v1.y);
  pk.u[3] = cvtpk_bf16(v1.z, v1.w);
  *(int4*)(out + i) = pk.v;
}

// ---------------- transpose + convert: W[K][N] f32 -> Wt[N][K] bf16 ----------------
__global__ __launch_bounds__(256) void k_transpose_f2b(const float* __restrict__ in,
                                                       unsigned short* __restrict__ out,
                                                       int K, int N){
  __shared__ float tile[32][33];
  int kb = blockIdx.y*32, nb = blockIdx.x*32;
  int tx = threadIdx.x, ty = threadIdx.y; // (32, 8)
  #pragma unroll
  for (int i=0;i<4;i++)
    tile[ty+i*8][tx] = in[(size_t)(kb+ty+i*8)*N + nb + tx];
  __syncthreads();
  #pragma unroll
  for (int i=0;i<4;i++)
    out[(size_t)(nb+ty+i*8)*K + kb + tx] = f2bf(tile[tx][ty+i*8]);
}

// ---------------- scan + tables fused: counts -> cumsum -> interleaved (cos,sin) ----------------
__global__ __launch_bounds__(1024) void k_scan(const int* __restrict__ tok,
                                               float* __restrict__ cs_t){
  __shared__ int cnt[2048];
  __shared__ float vals[2048];
  __shared__ float psum[1024];
  int b = blockIdx.x;
  int tid = threadIdx.x;
  cnt[tid] = 0; cnt[tid+1024] = 0;
  __syncthreads();
  // reference's fancy-indexing scatters ALL batches' tokens into every batch's counts
  for (int i = tid; i < Bb*Tt; i += 1024) atomicAdd(&cnt[tok[i]], 1);
  __syncthreads();
  for (int i = tid; i < Tt; i += 1024){
    int idx = tok[b*Tt + i];
    vals[i] = 1.0f / ((float)cnt[idx] + 1e-10f);
  }
  __syncthreads();
  float s0 = vals[2*tid], s1 = vals[2*tid+1];
  psum[tid] = s0 + s1;
  __syncthreads();
  for (int off=1; off<1024; off<<=1){
    float add = (tid>=off) ? psum[tid-off] : 0.0f;
    __syncthreads();
    psum[tid] += add;
    __syncthreads();
  }
  float base = (tid>0) ? psum[tid-1] : 0.0f;
  vals[2*tid]   = base + s0;
  vals[2*tid+1] = base + s0 + s1;
  __syncthreads();
  for (int i = tid; i < Tt*32; i += 1024){
    int t = i >> 5, j = i & 31;
    float invf = exp2f(-(float)j * 0.4152410118609203f);  // 10000^(-j/32)
    float ang = vals[t] * invf;
    float2 cs = make_float2(cosf(ang), sinf(ang));
    *(float2*)&cs_t[((size_t)b*Tt + t)*64 + 2*j] = cs;
  }
}

// ---------------- fused QKV GEMM, BK=64 (half the barriers): rope/overwrite/V-scale ----------------
// [128][64] LDS rows span all 32 banks; read group (4ks+lhi)^(R&7) is conflict-free
// under 8-lane phasing; source group g0^(r0&7) keeps 128B-contiguous global reads.
__global__ __launch_bounds__(256, 4) void k_gemmQKV(const unsigned short* __restrict__ A,
                                                    const unsigned short* __restrict__ Bt,
                                                    const float* __restrict__ bias,
                                                    const float* __restrict__ cs_t,
                                                    const float* __restrict__ cum,
                                                    unsigned short* __restrict__ Qo,
                                                    unsigned short* __restrict__ Ko,
                                                    unsigned short* __restrict__ VTo){
  __shared__ union {
    unsigned short ab[2][128][64];   // staging: [0]=A, [1]=B (32 KB)
    unsigned short vb[32][140];      // V transpose bounce (9 KB)
  } sm;
  const int K = 1024, N = 3072;
  int mb = blockIdx.y*128, nb = blockIdx.x*128;
  int tid = threadIdx.x;
  int wave = tid>>6, lane = tid&63;
  int wr = wave>>1, wc = wave&1;
  int lrow = lane&15, lhi = lane>>4;
  f32x4 acc[4][4] = {};
  int r0 = tid>>3;                       // 0..31 (stages rows r0+32i)
  int g0 = tid&7;                        // dest 16B group
  int gsw = (g0 ^ (r0&7)) << 3;          // inverse-swizzled source elem offset (same for all i)
  const unsigned short* Asrc = A  + (size_t)(mb + r0)*K + gsw;
  const unsigned short* Bsrc = Bt + (size_t)(nb + r0)*K + gsw;
  const size_t rstep = (size_t)32*K;
#ifdef USE_GLL
  for (int kb=0; kb<K; kb+=64){
    #pragma unroll
    for (int i=0;i<4;i++){
      __builtin_amdgcn_global_load_lds((const AS_GLOBAL void*)(Asrc + i*rstep + kb),
                                       (AS_LDS void*)&sm.ab[0][r0+32*i][g0*8], 16, 0, 0);
      __builtin_amdgcn_global_load_lds((const AS_GLOBAL void*)(Bsrc + i*rstep + kb),
                                       (AS_LDS void*)&sm.ab[1][r0+32*i][g0*8], 16, 0, 0);
    }
    __syncthreads();
    #pragma unroll
    for (int ks=0; ks<2; ks++){
      short8 af[4], bf[4];
      #pragma unroll
      for (int m=0;m<4;m++){
        int R = 64*wr + 16*m + lrow;
        af[m] = *(const short8*)&sm.ab[0][R][((4*ks+lhi)^(R&7))<<3];
      }
      #pragma unroll
      for (int n=0;n<4;n++){
        int R = 64*wc + 16*n + lrow;
        bf[n] = *(const short8*)&sm.ab[1][R][((4*ks+lhi)^(R&7))<<3];
      }
      #pragma unroll
      for (int m=0;m<4;m++)
        #pragma unroll
        for (int n=0;n<4;n++)
          acc[m][n] = __builtin_amdgcn_mfma_f32_16x16x32_bf16(af[m], bf[n], acc[m][n], 0,0,0);
    }
    __syncthreads();
  }
#else
  for (int kb=0; kb<K; kb+=64){
    int4 st[8];
    #pragma unroll
    for (int i=0;i<4;i++){
      st[2*i]   = *(const int4*)(Asrc + i*rstep + kb);
      st[2*i+1] = *(const int4*)(Bsrc + i*rstep + kb);
    }
    __syncthreads();
    #pragma unroll
    for (int i=0;i<4;i++){
      *(int4*)&sm.ab[0][r0+32*i][g0*8] = st[2*i];
      *(int4*)&sm.ab[1][r0+32*i][g0*8] = st[2*i+1];
    }
    __syncthreads();
    #pragma unroll
    for (int ks=0; ks<2; ks++){
      short8 af[4], bf[4];
      #pragma unroll
      for (int m=0;m<4;m++){
        int R = 64*wr + 16*m + lrow;
        af[m] = *(const short8*)&sm.ab[0][R][((4*ks+lhi)^(R&7))<<3];
      }
      #pragma unroll
      for (int n=0;n<4;n++){
        int R = 64*wc + 16*n + lrow;
        bf[n] = *(const short8*)&sm.ab[1][R][((4*ks+lhi)^(R&7))<<3];
      }
      #pragma unroll
      for (int m=0;m<4;m++)
        #pragma unroll
        for (int n=0;n<4;n++)
          acc[m][n] = __builtin_amdgcn_mfma_f32_16x16x32_bf16(af[m], bf[n], acc[m][n], 0,0,0);
    }
    __syncthreads();
  }
#endif
  int type = nb >> 10;                       // 0=Q 1=K 2=V
  int h0 = (nb >> 6) & 15;
  int h  = h0 + wc;                          // wave's head (64-col span = 1 head)
  int b_ = mb >> 11;
  int tb_ = mb & 2047;
  float bz[4];
  #pragma unroll
  for (int n=0;n<4;n++) bz[n] = bias[nb + 64*wc + 16*n + lrow];

  if (type < 2){
    unsigned short* dst = (type==0) ? Qo : Ko;
    #pragma unroll
    for (int m=0;m<4;m++)
      #pragma unroll
      for (int q=0;q<4;q++){
        int rl = 64*wr + 16*m + 4*lhi + q;
        int row = mb + rl;
        float2 cs0 = *(const float2*)&cs_t[(size_t)row*64 + 2*lrow];        // j=lrow
        float2 cs1 = *(const float2*)&cs_t[(size_t)row*64 + 32 + 2*lrow];   // j=16+lrow
        float a0 = acc[m][0][q] + bz[0];   // d = lrow
        float a1 = acc[m][1][q] + bz[1];   // d = 16+lrow
        float a2 = acc[m][2][q] + bz[2];   // d = 32+lrow
        float a3 = acc[m][3][q] + bz[3];   // d = 48+lrow
        float r0v = a0*cs0.x - a2*cs0.y;
        float r1v = a1*cs1.x - a3*cs1.y;
        float r2v = a2*cs0.x + a0*cs0.y;
        float r3v = a3*cs1.x + a1*cs1.y;
        if (type==0){
          if (lrow==15) r3v = 1.0f;                 // q[...,-1] = 1 (then scaled)
          r0v *= QSCALE; r1v *= QSCALE; r2v *= QSCALE; r3v *= QSCALE;
        } else {
          if (lrow==15) r3v = cum[row];             // k[...,-1] = cumulative_scores
        }
        size_t base = (((size_t)b_*Hh + h)*Tt + (row & 2047))*HDd + lrow;
        dst[base]      = f2bf(r0v);
        dst[base + 16] = f2bf(r1v);
        dst[base + 32] = f2bf(r2v);
        dst[base + 48] = f2bf(r3v);
      }
  } else {
    // V: scale by exp(cum), transpose via 4 passes of 32 t-rows through 9KB LDS
    for (int pass=0; pass<4; pass++){
      __syncthreads();
      if (wr == (pass>>1)){
        int m0 = 2*(pass&1);
        #pragma unroll
        for (int mm=0; mm<2; mm++){
          int m = m0 + mm;
          #pragma unroll
          for (int q=0;q<4;q++){
            int rl32 = 16*mm + 4*lhi + q;          // row within the 32-row chunk
            float vs = __expf(cum[mb + 32*pass + rl32]);
            sm.vb[rl32][64*wc + lrow]      = f2bf((acc[m][0][q]+bz[0])*vs);
            sm.vb[rl32][64*wc + 16+lrow]   = f2bf((acc[m][1][q]+bz[1])*vs);
            sm.vb[rl32][64*wc + 32+lrow]   = f2bf((acc[m][2][q]+bz[2])*vs);
            sm.vb[rl32][64*wc + 48+lrow]   = f2bf((acc[m][3][q]+bz[3])*vs);
          }
        }
      }
      __syncthreads();
      #pragma unroll
      for (int i=0;i<16;i++){
        int idx = i*256 + tid;
        int t_l = idx & 31;
        int dh  = idx >> 5;          // 0..127
        int d   = dh & 63;
        int hh  = dh >> 6;
        VTo[(((size_t)b_*Hh + h0 + hh)*HDd + d)*Tt + tb_ + 32*pass + t_l] = sm.vb[t_l][64*hh + d];
      }
    }
  }
}

// ---------------- 64x128-tile GEMM (fp32 out, 2-way-swizzled LDS) for proj ----------------
__global__ __launch_bounds__(256) void k_gemm64(const unsigned short* __restrict__ A,
                                                const unsigned short* __restrict__ Bt,
                                                const float* __restrict__ bias,
                                                float* __restrict__ Cout,
                                                int M, int N, int K){
  __shared__ unsigned short As[64][32];
  __shared__ unsigned short Bs[128][32];
  int mb = blockIdx.y*64, nb = blockIdx.x*128;
  int tid = threadIdx.x;
  int wave = tid>>6, lane = tid&63;
  int wr = wave>>1, wc = wave&1;
  int lrow = lane&15, lhi = lane>>4;
  f32x4 acc[2][4] = {};
  int r0 = tid>>2;
  int gd = tid&3;
  int gs0 = (gd ^ ((r0>>1)&3)) << 3;
  const unsigned short* Arow  = A  + (size_t)(mb + r0)*K      + gs0;
  const unsigned short* Brow0 = Bt + (size_t)(nb + r0)*K      + gs0;
  const unsigned short* Brow1 = Bt + (size_t)(nb + r0 + 64)*K + gs0;
#ifdef USE_GLL
  for (int kb=0; kb<K; kb+=32){
    __builtin_amdgcn_global_load_lds((const AS_GLOBAL void*)(Arow + kb),
                                     (AS_LDS void*)&As[r0][gd*8],    16, 0, 0);
    __builtin_amdgcn_global_load_lds((const AS_GLOBAL void*)(Brow0 + kb),
                                     (AS_LDS void*)&Bs[r0][gd*8],    16, 0, 0);
    __builtin_amdgcn_global_load_lds((const AS_GLOBAL void*)(Brow1 + kb),
                                     (AS_LDS void*)&Bs[r0+64][gd*8], 16, 0, 0);
    __syncthreads();
    short8 af[2], bf[4];
    #pragma unroll
    for (int m=0;m<2;m++){
      int R = 32*wr + 16*m + lrow;
      af[m] = *(const short8*)&As[R][(lhi^((R>>1)&3))<<3];
    }
    #pragma unroll
    for (int n=0;n<4;n++){
      int R = 64*wc + 16*n + lrow;
      bf[n] = *(const short8*)&Bs[R][(lhi^((R>>1)&3))<<3];
    }
    #pragma unroll
    for (int m=0;m<2;m++)
      #pragma unroll
      for (int n=0;n<4;n++)
        acc[m][n] = __builtin_amdgcn_mfma_f32_16x16x32_bf16(af[m], bf[n], acc[m][n], 0,0,0);
    __syncthreads();
  }
#else
  for (int kb=0; kb<K; kb+=32){
    int4 a0 = *(const int4*)(Arow + kb);
    int4 b0 = *(const int4*)(Brow0 + kb);
    int4 b1 = *(const int4*)(Brow1 + kb);
    __syncthreads();
    *(int4*)&As[r0][gd*8]    = a0;
    *(int4*)&Bs[r0][gd*8]    = b0;
    *(int4*)&Bs[r0+64][gd*8] = b1;
    __syncthreads();
    short8 af[2], bf[4];
    #pragma unroll
    for (int m=0;m<2;m++){
      int R = 32*wr + 16*m + lrow;
      af[m] = *(const short8*)&As[R][(lhi^((R>>1)&3))<<3];
    }
    #pragma unroll
    for (int n=0;n<4;n++){
      int R = 64*wc + 16*n + lrow;
      bf[n] = *(const short8*)&Bs[R][(lhi^((R>>1)&3))<<3];
    }
    #pragma unroll
    for (int m=0;m<2;m++)
      #pragma unroll
      for (int n=0;n<4;n++)
        acc[m][n] = __builtin_amdgcn_mfma_f32_16x16x32_bf16(af[m], bf[n], acc[m][n], 0,0,0);
  }
#endif
  #pragma unroll
  for (int m=0;m<2;m++)
    #pragma unroll
    for (int n=0;n<4;n++)
      #pragma unroll
      for (int q=0;q<4;q++){
        int row = mb + 32*wr + 16*m + 4*lhi + q;
        int col = nb + 64*wc + 16*n + lrow;
        Cout[(size_t)row*N + col] = acc[m][n][q] + bias[col];
      }
}

// ---------------- flash attention v11: single-buffer 36KB LDS, 4 blocks/CU ----------------
// Round-12 structure with the launch-bounds bug fixed: (512,4) caps VGPR at 128
// (actual 64, proven no-spill in r13); 36KB LDS -> 4 blocks/CU -> 8 waves/SIMD.
__global__ __launch_bounds__(512, 4) void k_attn11(const unsigned short* __restrict__ Q,
                                                   const unsigned short* __restrict__ K,
                                                   const unsigned short* __restrict__ VT,
                                                   unsigned short* __restrict__ Y){
  __shared__ __align__(16) char smem[36864];
  unsigned short (*Ks)[4096] = (unsigned short (*)[4096])smem;           // [2 parities][8KB]
  unsigned short (*Vs)[4096] = (unsigned short (*)[4096])(smem + 16384);
  float (*cmb)[64][35] = (float (*)[64][35])smem;   // overlay after final barrier (35840B)

  int bh = blockIdx.y; int b = bh >> 4, h = bh & 15;
  int s_ = blockIdx.x;
  int tid = threadIdx.x;
  int wave = tid>>6, lane = tid&63;
  int wpair = wave & 3, p = wave >> 2;
  int lrow = lane&15, lhi = lane>>4;
  const unsigned short* Qh = Q + (((size_t)b*Hh + h)*Tt)*HDd;
  const unsigned short* Kh = K + (((size_t)b*Hh + h)*Tt)*HDd;
  const unsigned short* Vh = VT + (((size_t)b*Hh + h)*HDd)*Tt;
  int qL0 = 64*s_ + 16*wpair;
  int qH0 = 1984 - 64*s_ + 16*wpair;
  short8 qfL0 = *(const short8*)&Qh[(size_t)(qL0+lrow)*HDd + 8*lhi];
  short8 qfL1 = *(const short8*)&Qh[(size_t)(qL0+lrow)*HDd + 32 + 8*lhi];
  short8 qfH0 = *(const short8*)&Qh[(size_t)(qH0+lrow)*HDd + 8*lhi];
  short8 qfH1 = *(const short8*)&Qh[(size_t)(qH0+lrow)*HDd + 32 + 8*lhi];
  f32x4 oL[4] = {}, oH[4] = {};             // O^T: [jp] -> O[q=lrow][d=16jp+4lhi+r]
  float lsL = 0.0f, lsH = 0.0f;
  int rowL = qL0 + lrow, rowH = qH0 + lrow;
  int ntL = s_ + 1;
  int NTH = 32 - s_;
  int NI  = (NTH + 1) >> 1;

  int kr = tid >> 3, kc = tid & 7;
  int o_ = tid * 16;
  int ksrc = kr*HDd + ((kc ^ (kr&7)) << 3);
  int vsrc = kr*Tt  + ((kc ^ (kr&7)) << 3);

#ifdef USE_GLL
#define STAGE2(base_) do { \
    __builtin_amdgcn_global_load_lds((const AS_GLOBAL void*)(Kh + (size_t)(base_)*64*HDd + ksrc), \
        (AS_LDS void*)((AS_LDS char*)&Ks[0][0] + o_), 16, 0, 0); \
    __builtin_amdgcn_global_load_lds((const AS_GLOBAL void*)(Vh + (size_t)(base_)*64 + vsrc), \
        (AS_LDS void*)((AS_LDS char*)&Vs[0][0] + o_), 16, 0, 0); \
    if ((base_)+1 < NTH){ \
      __builtin_amdgcn_global_load_lds((const AS_GLOBAL void*)(Kh + (size_t)((base_)+1)*64*HDd + ksrc), \
          (AS_LDS void*)((AS_LDS char*)&Ks[1][0] + o_), 16, 0, 0); \
      __builtin_amdgcn_global_load_lds((const AS_GLOBAL void*)(Vh + (size_t)((base_)+1)*64 + vsrc), \
          (AS_LDS void*)((AS_LDS char*)&Vs[1][0] + o_), 16, 0, 0); \
    } \
  } while(0)
#else
#define STAGE2(base_) do { \
    int4 a_ = *(const int4*)(Kh + (size_t)(base_)*64*HDd + ksrc); \
    int4 c_ = *(const int4*)(Vh + (size_t)(base_)*64 + vsrc); \
    *(int4*)((char*)&Ks[0][0] + o_) = a_; \
    *(int4*)((char*)&Vs[0][0] + o_) = c_; \
    if ((base_)+1 < NTH){ \
      int4 b_ = *(const int4*)(Kh + (size_t)((base_)+1)*64*HDd + ksrc); \
      int4 d_ = *(const int4*)(Vh + (size_t)((base_)+1)*64 + vsrc); \
      *(int4*)((char*)&Ks[1][0] + o_) = b_; \
      *(int4*)((char*)&Vs[1][0] + o_) = d_; \
    } \
  } while(0)
#endif

  for (int i = 0; i < NI; i++){
    __syncthreads();                 // prior iteration's reads complete
    STAGE2(2*i);
    __syncthreads();                 // staging landed (compiler drains vmcnt)
    int kt = 2*i + p;
    if (kt < NTH){
      int k0 = kt*64;
      bool doL = (kt < ntL);
      const unsigned short* Kbase = &Ks[p][0];
      const unsigned short* Vbase = &Vs[p][0];
      f32x4 sL[4] = {}, sH[4] = {};
      __builtin_amdgcn_s_setprio(1);
      #pragma unroll
      for (int j=0;j<4;j++){
        int krow = 16*j + lrow;
        #pragma unroll
        for (int ks=0;ks<2;ks++){
          int dgrp = (4*ks + lhi) ^ (krow&7);
          short8 kf = *(const short8*)&Kbase[krow*64 + dgrp*8];
          sH[j] = __builtin_amdgcn_mfma_f32_16x16x32_bf16(kf, ks ? qfH1 : qfH0, sH[j], 0,0,0);
          if (doL) sL[j] = __builtin_amdgcn_mfma_f32_16x16x32_bf16(kf, ks ? qfL1 : qfL0, sL[j], 0,0,0);
        }
      }
      __builtin_amdgcn_s_setprio(0);
      short4v paH[4], paL[4];
      {
        bool diagH = (k0 + 63 >= qH0);
        #pragma unroll
        for (int j=0;j<4;j++){
          int kbase = k0 + 16*j + 4*lhi;
          float p0 = exp2fast(sH[j][0]);
          float p1 = exp2fast(sH[j][1]);
          float p2 = exp2fast(sH[j][2]);
          float p3 = exp2fast(sH[j][3]);
          if (diagH){
            if (kbase + 0 > rowH) p0 = 0.0f;
            if (kbase + 1 > rowH) p1 = 0.0f;
            if (kbase + 2 > rowH) p2 = 0.0f;
            if (kbase + 3 > rowH) p3 = 0.0f;
          }
          lsH += (p0 + p1) + (p2 + p3);
          union { unsigned int u[2]; short4v v; } pk;
          pk.u[0] = cvtpk_bf16(p0, p1);
          pk.u[1] = cvtpk_bf16(p2, p3);
          paH[j] = pk.v;
        }
      }
      if (doL){
        bool diagL = (k0 + 63 >= qL0);
        #pragma unroll
        for (int j=0;j<4;j++){
          int kbase = k0 + 16*j + 4*lhi;
          float p0 = exp2fast(sL[j][0]);
          float p1 = exp2fast(sL[j][1]);
          float p2 = exp2fast(sL[j][2]);
          float p3 = exp2fast(sL[j][3]);
          if (diagL){
            if (kbase + 0 > rowL) p0 = 0.0f;
            if (kbase + 1 > rowL) p1 = 0.0f;
            if (kbase + 2 > rowL) p2 = 0.0f;
            if (kbase + 3 > rowL) p3 = 0.0f;
          }
          lsL += (p0 + p1) + (p2 + p3);
          union { unsigned int u[2]; short4v v; } pk;
          pk.u[0] = cvtpk_bf16(p0, p1);
          pk.u[1] = cvtpk_bf16(p2, p3);
          paL[j] = pk.v;
        }
      }
      __builtin_amdgcn_s_setprio(1);
      #pragma unroll
      for (int jp=0;jp<4;jp++){
        int vrow = 16*jp + lrow;
        #pragma unroll
        for (int j=0;j<4;j++){
          int byte_in_row = ((((2*j + (lhi>>1)) ^ (vrow&7)) << 4) | ((lhi&1) << 3));
          short4v vf = *(const short4v*)((const char*)&Vbase[vrow*64] + byte_in_row);
          oH[jp] = mfma16(vf, paH[j], oH[jp]);       // A=V^T frag, B=P^T frag
          if (doL) oL[jp] = mfma16(vf, paL[j], oL[jp]);
        }
      }
      __builtin_amdgcn_s_setprio(0);
    }
  }

  __syncthreads();                    // all compute done; smem reusable as cmb
  if (p == 1){
    float* c = &cmb[wpair][lane][0];
    #pragma unroll
    for (int jp=0;jp<4;jp++)
      #pragma unroll
      for (int r=0;r<4;r++){
        c[4*jp+r]    = oL[jp][r];
        c[16+4*jp+r] = oH[jp][r];
      }
    c[32] = lsL; c[33] = lsH;
  }
  __syncthreads();
  if (p == 0){
    const float* c = &cmb[wpair][lane][0];
    #pragma unroll
    for (int jp=0;jp<4;jp++)
      #pragma unroll
      for (int r=0;r<4;r++){
        oL[jp][r] += c[4*jp+r];
        oH[jp][r] += c[16+4*jp+r];
      }
    lsL += c[32]; lsH += c[33];
    lsL += __shfl_xor(lsL, 16); lsL += __shfl_xor(lsL, 32);
    lsH += __shfl_xor(lsH, 16); lsH += __shfl_xor(lsH, 32);
    float invL = 1.0f / lsL, invH = 1.0f / lsH;
    size_t rbL = ((size_t)b*Tt + qL0 + lrow)*Cc + h*HDd + 4*lhi;
    size_t rbH = ((size_t)b*Tt + qH0 + lrow)*Cc + h*HDd + 4*lhi;
    #pragma unroll
    for (int jp=0;jp<4;jp++){
      unsigned int l0 = cvtpk_bf16(oL[jp][0]*invL, oL[jp][1]*invL);
      unsigned int l1 = cvtpk_bf16(oL[jp][2]*invL, oL[jp][3]*invL);
      unsigned int h0_ = cvtpk_bf16(oH[jp][0]*invH, oH[jp][1]*invH);
      unsigned int h1_ = cvtpk_bf16(oH[jp][2]*invH, oH[jp][3]*invH);
      *(unsigned long long*)&Y[rbL + 16*jp] = (unsigned long long)l0 | ((unsigned long long)l1<<32);
      *(unsigned long long*)&Y[rbH + 16*jp] = (unsigned long long)h0_ | ((unsigned long long)h1_<<32);
    }
  }
#undef STAGE2
}

extern "C" void kernel_launch(void* const* d_in, const int* in_sizes, int n_in,
                              void* d_out, int out_size, void* d_ws, size_t ws_size,
                              hipStream_t stream){
  const float* x     = (const float*)d_in[0];
  const float* cum   = (const float*)d_in[1];
  const int*   tok   = (const int*)d_in[3];
  const float* Wqkv  = (const float*)d_in[4];
  const float* bqkv  = (const float*)d_in[5];
  const float* Wproj = (const float*)d_in[6];
  const float* bproj = (const float*)d_in[7];

  char* ws = (char*)d_ws;
  size_t off = 0;
  auto alloc = [&](size_t bytes)->void*{
    void* p = ws + off; off += (bytes + 255) & ~(size_t)255; return p;
  };
  unsigned short* wqkvT = (unsigned short*)alloc((size_t)3072*1024*2);
  unsigned short* wprojT= (unsigned short*)alloc((size_t)1024*1024*2);
  unsigned short* xb    = (unsigned short*)alloc((size_t)4096*1024*2); // reused as Y
  unsigned short* Qb    = (unsigned short*)alloc((size_t)Bb*Hh*Tt*HDd*2);
  unsigned short* Kb    = (unsigned short*)alloc((size_t)Bb*Hh*Tt*HDd*2);
  unsigned short* VTb   = (unsigned short*)alloc((size_t)Bb*Hh*Tt*HDd*2);
  float* cs_t           = (float*)alloc((size_t)Bb*Tt*64*4);
  unsigned short* Y     = xb; // alias: xb dead after QKV GEMM

  k_f2b<<<dim3(4096*1024/8/256), dim3(256), 0, stream>>>(x, xb, 4096*1024);
  k_transpose_f2b<<<dim3(3072/32, 1024/32), dim3(32,8), 0, stream>>>(Wqkv, wqkvT, 1024, 3072);
  k_transpose_f2b<<<dim3(1024/32, 1024/32), dim3(32,8), 0, stream>>>(Wproj, wprojT, 1024, 1024);
  k_scan<<<dim3(Bb), dim3(1024), 0, stream>>>(tok, cs_t);
  k_gemmQKV<<<dim3(3072/128, 4096/128), dim3(256), 0, stream>>>(xb, wqkvT, bqkv, cs_t, cum, Qb, Kb, VTb);
  k_attn11<<<dim3(16, Bb*Hh), dim3(512), 0, stream>>>(Qb, Kb, VTb, Y);
  k_gemm64<<<dim3(1024/128, 4096/64), dim3(256), 0, stream>>>(Y, wprojT, bproj, (float*)d_out, 4096, 1024, 1024);
}

// Round 15
// 133.659 us; speedup vs baseline: 1.0331x; 1.0331x over previous
//
#include <hip/hip_runtime.h>
#include <hip/hip_bf16.h>
#include <math.h>

#define Bb 2
#define Tt 2048
#define Cc 1024
#define Hh 16
#define HDd 64
#define QSCALE 0.18033688011112042f   // 0.125 * log2(e): folds softmax scale + exp->exp2

typedef __attribute__((ext_vector_type(8))) short short8;
typedef __attribute__((ext_vector_type(4))) short short4v;
typedef __attribute__((ext_vector_type(4))) float f32x4;

#if defined(__has_builtin)
#if __has_builtin(__builtin_amdgcn_global_load_lds)
#define USE_GLL 1
#endif
#endif
#define AS_GLOBAL __attribute__((address_space(1)))
#define AS_LDS    __attribute__((address_space(3)))

__device__ __forceinline__ float bf2f(unsigned short u){
  union { unsigned int i; float f; } v; v.i = ((unsigned int)u)<<16; return v.f;
}
__device__ __forceinline__ unsigned short f2bf(float f){
  union { float f; unsigned int i; } v; v.f = f;
  unsigned int x = v.i;
  return (unsigned short)((x + 0x7fffu + ((x>>16)&1u)) >> 16);
}
__device__ __forceinline__ unsigned int cvtpk_bf16(float lo, float hi){
  unsigned int r;
  asm("v_cvt_pk_bf16_f32 %0, %1, %2" : "=v"(r) : "v"(lo), "v"(hi));
  return r;
}
__device__ __forceinline__ float exp2fast(float x){
  float r; asm("v_exp_f32 %0, %1" : "=v"(r) : "v"(x)); return r;
}
__device__ __forceinline__ f32x4 mfma16(short4v a, short4v b, f32x4 c){
#if defined(__has_builtin)
#if __has_builtin(__builtin_amdgcn_mfma_f32_16x16x16_bf16)
  return __builtin_amdgcn_mfma_f32_16x16x16_bf16(a, b, c, 0, 0, 0);
#elif __has_builtin(__builtin_amdgcn_mfma_f32_16x16x16bf16_1k)
  return __builtin_amdgcn_mfma_f32_16x16x16bf16_1k(a, b, c, 0, 0, 0);
#else
  asm("v_mfma_f32_16x16x16_bf16 %0, %1, %2, %3" : "=v"(c) : "v"(a), "v"(b), "0"(c));
  return c;
#endif
#else
  asm("v_mfma_f32_16x16x16_bf16 %0, %1, %2, %3" : "=v"(c) : "v"(a), "v"(b), "0"(c));
  return c;
#endif
}

// ---------------- fp32 -> bf16 convert (8 elems/thread, 16B stores) ----------------
__global__ __launch_bounds__(256) void k_f2b(const float* __restrict__ in,
                                             unsigned short* __restrict__ out, int n){
  int i = (blockIdx.x*256 + threadIdx.x)*8;
  if (i >= n) return;
  float4 v0 = *(const float4*)(in + i);
  float4 v1 = *(const float4*)(in + i + 4);
  union { unsigned int u[4]; int4 v; } pk;
  pk.u[0] = cvtpk_bf16(v0.x, v0.y);
  pk.u[1] = cvtpk_bf16(v0.z, v0.w);
  pk.u[2] = cvtpk_bf16(v1.x, v1.y);
  pk.u[3] = cvtpk_bf16(v1.z, v1.w);
  *(int4*)(out + i) = pk.v;
}

// ---------------- transpose + convert both weights: W[K][N] f32 -> Wt[N][K] bf16 ----------------
// grid.z = 0 -> Wqkv (N=3072), 1 -> Wproj (N=1024); K=1024 for both.
__global__ __launch_bounds__(256) void k_transpose_f2b(const float* __restrict__ w0,
                                                       const float* __restrict__ w1,
                                                       unsigned short* __restrict__ o0,
                                                       unsigned short* __restrict__ o1){
  __shared__ float tile[32][33];
  const int K = 1024;
  int which = blockIdx.z;
  const float* in = which ? w1 : w0;
  unsigned short* out = which ? o1 : o0;
  int N = which ? 1024 : 3072;
  if (blockIdx.x*32 >= N) return;
  int kb = blockIdx.y*32, nb = blockIdx.x*32;
  int tx = threadIdx.x, ty = threadIdx.y; // (32, 8)
  #pragma unroll
  for (int i=0;i<4;i++)
    tile[ty+i*8][tx] = in[(size_t)(kb+ty+i*8)*N + nb + tx];
  __syncthreads();
  #pragma unroll
  for (int i=0;i<4;i++)
    out[(size_t)(nb+ty+i*8)*K + kb + tx] = f2bf(tile[tx][ty+i*8]);
}

// ---------------- scan + tables fused: counts -> cumsum -> interleaved (cos,sin) ----------------
__global__ __launch_bounds__(1024) void k_scan(const int* __restrict__ tok,
                                               float* __restrict__ cs_t){
  __shared__ int cnt[2048];
  __shared__ float vals[2048];
  __shared__ float psum[1024];
  int b = blockIdx.x;
  int tid = threadIdx.x;
  cnt[tid] = 0; cnt[tid+1024] = 0;
  __syncthreads();
  // reference's fancy-indexing scatters ALL batches' tokens into every batch's counts
  for (int i = tid; i < Bb*Tt; i += 1024) atomicAdd(&cnt[tok[i]], 1);
  __syncthreads();
  for (int i = tid; i < Tt; i += 1024){
    int idx = tok[b*Tt + i];
    vals[i] = 1.0f / ((float)cnt[idx] + 1e-10f);
  }
  __syncthreads();
  float s0 = vals[2*tid], s1 = vals[2*tid+1];
  psum[tid] = s0 + s1;
  __syncthreads();
  for (int off=1; off<1024; off<<=1){
    float add = (tid>=off) ? psum[tid-off] : 0.0f;
    __syncthreads();
    psum[tid] += add;
    __syncthreads();
  }
  float base = (tid>0) ? psum[tid-1] : 0.0f;
  vals[2*tid]   = base + s0;
  vals[2*tid+1] = base + s0 + s1;
  __syncthreads();
  for (int i = tid; i < Tt*32; i += 1024){
    int t = i >> 5, j = i & 31;
    float invf = exp2f(-(float)j * 0.4152410118609203f);  // 10000^(-j/32)
    float ang = vals[t] * invf;
    float2 cs = make_float2(cosf(ang), sinf(ang));
    *(float2*)&cs_t[((size_t)b*Tt + t)*64 + 2*j] = cs;
  }
}

// ---------------- fused QKV GEMM, BK=64: rope/overwrite/V-scale epilogue ----------------
__global__ __launch_bounds__(256, 4) void k_gemmQKV(const unsigned short* __restrict__ A,
                                                    const unsigned short* __restrict__ Bt,
                                                    const float* __restrict__ bias,
                                                    const float* __restrict__ cs_t,
                                                    const float* __restrict__ cum,
                                                    unsigned short* __restrict__ Qo,
                                                    unsigned short* __restrict__ Ko,
                                                    unsigned short* __restrict__ VTo){
  __shared__ union {
    unsigned short ab[2][128][64];   // staging: [0]=A, [1]=B (32 KB)
    unsigned short vb[32][140];      // V transpose bounce (9 KB)
  } sm;
  const int K = 1024, N = 3072;
  int mb = blockIdx.y*128, nb = blockIdx.x*128;
  int tid = threadIdx.x;
  int wave = tid>>6, lane = tid&63;
  int wr = wave>>1, wc = wave&1;
  int lrow = lane&15, lhi = lane>>4;
  f32x4 acc[4][4] = {};
  int r0 = tid>>3;                       // 0..31 (stages rows r0+32i)
  int g0 = tid&7;                        // dest 16B group
  int gsw = (g0 ^ (r0&7)) << 3;          // inverse-swizzled source elem offset
  const unsigned short* Asrc = A  + (size_t)(mb + r0)*K + gsw;
  const unsigned short* Bsrc = Bt + (size_t)(nb + r0)*K + gsw;
  const size_t rstep = (size_t)32*K;
#ifdef USE_GLL
  for (int kb=0; kb<K; kb+=64){
    #pragma unroll
    for (int i=0;i<4;i++){
      __builtin_amdgcn_global_load_lds((const AS_GLOBAL void*)(Asrc + i*rstep + kb),
                                       (AS_LDS void*)&sm.ab[0][r0+32*i][g0*8], 16, 0, 0);
      __builtin_amdgcn_global_load_lds((const AS_GLOBAL void*)(Bsrc + i*rstep + kb),
                                       (AS_LDS void*)&sm.ab[1][r0+32*i][g0*8], 16, 0, 0);
    }
    __syncthreads();
    #pragma unroll
    for (int ks=0; ks<2; ks++){
      short8 af[4], bf[4];
      #pragma unroll
      for (int m=0;m<4;m++){
        int R = 64*wr + 16*m + lrow;
        af[m] = *(const short8*)&sm.ab[0][R][((4*ks+lhi)^(R&7))<<3];
      }
      #pragma unroll
      for (int n=0;n<4;n++){
        int R = 64*wc + 16*n + lrow;
        bf[n] = *(const short8*)&sm.ab[1][R][((4*ks+lhi)^(R&7))<<3];
      }
      #pragma unroll
      for (int m=0;m<4;m++)
        #pragma unroll
        for (int n=0;n<4;n++)
          acc[m][n] = __builtin_amdgcn_mfma_f32_16x16x32_bf16(af[m], bf[n], acc[m][n], 0,0,0);
    }
    __syncthreads();
  }
#else
  for (int kb=0; kb<K; kb+=64){
    int4 st[8];
    #pragma unroll
    for (int i=0;i<4;i++){
      st[2*i]   = *(const int4*)(Asrc + i*rstep + kb);
      st[2*i+1] = *(const int4*)(Bsrc + i*rstep + kb);
    }
    __syncthreads();
    #pragma unroll
    for (int i=0;i<4;i++){
      *(int4*)&sm.ab[0][r0+32*i][g0*8] = st[2*i];
      *(int4*)&sm.ab[1][r0+32*i][g0*8] = st[2*i+1];
    }
    __syncthreads();
    #pragma unroll
    for (int ks=0; ks<2; ks++){
      short8 af[4], bf[4];
      #pragma unroll
      for (int m=0;m<4;m++){
        int R = 64*wr + 16*m + lrow;
        af[m] = *(const short8*)&sm.ab[0][R][((4*ks+lhi)^(R&7))<<3];
      }
      #pragma unroll
      for (int n=0;n<4;n++){
        int R = 64*wc + 16*n + lrow;
        bf[n] = *(const short8*)&sm.ab[1][R][((4*ks+lhi)^(R&7))<<3];
      }
      #pragma unroll
      for (int m=0;m<4;m++)
        #pragma unroll
        for (int n=0;n<4;n++)
          acc[m][n] = __builtin_amdgcn_mfma_f32_16x16x32_bf16(af[m], bf[n], acc[m][n], 0,0,0);
    }
    __syncthreads();
  }
#endif
  int type = nb >> 10;                       // 0=Q 1=K 2=V
  int h0 = (nb >> 6) & 15;
  int h  = h0 + wc;                          // wave's head (64-col span = 1 head)
  int b_ = mb >> 11;
  int tb_ = mb & 2047;
  float bz[4];
  #pragma unroll
  for (int n=0;n<4;n++) bz[n] = bias[nb + 64*wc + 16*n + lrow];

  if (type < 2){
    unsigned short* dst = (type==0) ? Qo : Ko;
    #pragma unroll
    for (int m=0;m<4;m++)
      #pragma unroll
      for (int q=0;q<4;q++){
        int rl = 64*wr + 16*m + 4*lhi + q;
        int row = mb + rl;
        float2 cs0 = *(const float2*)&cs_t[(size_t)row*64 + 2*lrow];        // j=lrow
        float2 cs1 = *(const float2*)&cs_t[(size_t)row*64 + 32 + 2*lrow];   // j=16+lrow
        float a0 = acc[m][0][q] + bz[0];   // d = lrow
        float a1 = acc[m][1][q] + bz[1];   // d = 16+lrow
        float a2 = acc[m][2][q] + bz[2];   // d = 32+lrow
        float a3 = acc[m][3][q] + bz[3];   // d = 48+lrow
        float r0v = a0*cs0.x - a2*cs0.y;
        float r1v = a1*cs1.x - a3*cs1.y;
        float r2v = a2*cs0.x + a0*cs0.y;
        float r3v = a3*cs1.x + a1*cs1.y;
        if (type==0){
          if (lrow==15) r3v = 1.0f;                 // q[...,-1] = 1 (then scaled)
          r0v *= QSCALE; r1v *= QSCALE; r2v *= QSCALE; r3v *= QSCALE;
        } else {
          if (lrow==15) r3v = cum[row];             // k[...,-1] = cumulative_scores
        }
        size_t base = (((size_t)b_*Hh + h)*Tt + (row & 2047))*HDd + lrow;
        dst[base]      = f2bf(r0v);
        dst[base + 16] = f2bf(r1v);
        dst[base + 32] = f2bf(r2v);
        dst[base + 48] = f2bf(r3v);
      }
  } else {
    // V: scale by exp(cum), transpose via 4 passes of 32 t-rows through 9KB LDS
    for (int pass=0; pass<4; pass++){
      __syncthreads();
      if (wr == (pass>>1)){
        int m0 = 2*(pass&1);
        #pragma unroll
        for (int mm=0; mm<2; mm++){
          int m = m0 + mm;
          #pragma unroll
          for (int q=0;q<4;q++){
            int rl32 = 16*mm + 4*lhi + q;          // row within the 32-row chunk
            float vs = __expf(cum[mb + 32*pass + rl32]);
            sm.vb[rl32][64*wc + lrow]      = f2bf((acc[m][0][q]+bz[0])*vs);
            sm.vb[rl32][64*wc + 16+lrow]   = f2bf((acc[m][1][q]+bz[1])*vs);
            sm.vb[rl32][64*wc + 32+lrow]   = f2bf((acc[m][2][q]+bz[2])*vs);
            sm.vb[rl32][64*wc + 48+lrow]   = f2bf((acc[m][3][q]+bz[3])*vs);
          }
        }
      }
      __syncthreads();
      #pragma unroll
      for (int i=0;i<16;i++){
        int idx = i*256 + tid;
        int t_l = idx & 31;
        int dh  = idx >> 5;          // 0..127
        int d   = dh & 63;
        int hh  = dh >> 6;
        VTo[(((size_t)b_*Hh + h0 + hh)*HDd + d)*Tt + tb_ + 32*pass + t_l] = sm.vb[t_l][64*hh + d];
      }
    }
  }
}

// ---------------- 64x128-tile GEMM (fp32 out, 2-way-swizzled LDS) for proj ----------------
__global__ __launch_bounds__(256) void k_gemm64(const unsigned short* __restrict__ A,
                                                const unsigned short* __restrict__ Bt,
                                                const float* __restrict__ bias,
                                                float* __restrict__ Cout,
                                                int M, int N, int K){
  __shared__ unsigned short As[64][32];
  __shared__ unsigned short Bs[128][32];
  int mb = blockIdx.y*64, nb = blockIdx.x*128;
  int tid = threadIdx.x;
  int wave = tid>>6, lane = tid&63;
  int wr = wave>>1, wc = wave&1;
  int lrow = lane&15, lhi = lane>>4;
  f32x4 acc[2][4] = {};
  int r0 = tid>>2;
  int gd = tid&3;
  int gs0 = (gd ^ ((r0>>1)&3)) << 3;
  const unsigned short* Arow  = A  + (size_t)(mb + r0)*K      + gs0;
  const unsigned short* Brow0 = Bt + (size_t)(nb + r0)*K      + gs0;
  const unsigned short* Brow1 = Bt + (size_t)(nb + r0 + 64)*K + gs0;
#ifdef USE_GLL
  for (int kb=0; kb<K; kb+=32){
    __builtin_amdgcn_global_load_lds((const AS_GLOBAL void*)(Arow + kb),
                                     (AS_LDS void*)&As[r0][gd*8],    16, 0, 0);
    __builtin_amdgcn_global_load_lds((const AS_GLOBAL void*)(Brow0 + kb),
                                     (AS_LDS void*)&Bs[r0][gd*8],    16, 0, 0);
    __builtin_amdgcn_global_load_lds((const AS_GLOBAL void*)(Brow1 + kb),
                                     (AS_LDS void*)&Bs[r0+64][gd*8], 16, 0, 0);
    __syncthreads();
    short8 af[2], bf[4];
    #pragma unroll
    for (int m=0;m<2;m++){
      int R = 32*wr + 16*m + lrow;
      af[m] = *(const short8*)&As[R][(lhi^((R>>1)&3))<<3];
    }
    #pragma unroll
    for (int n=0;n<4;n++){
      int R = 64*wc + 16*n + lrow;
      bf[n] = *(const short8*)&Bs[R][(lhi^((R>>1)&3))<<3];
    }
    #pragma unroll
    for (int m=0;m<2;m++)
      #pragma unroll
      for (int n=0;n<4;n++)
        acc[m][n] = __builtin_amdgcn_mfma_f32_16x16x32_bf16(af[m], bf[n], acc[m][n], 0,0,0);
    __syncthreads();
  }
#else
  for (int kb=0; kb<K; kb+=32){
    int4 a0 = *(const int4*)(Arow + kb);
    int4 b0 = *(const int4*)(Brow0 + kb);
    int4 b1 = *(const int4*)(Brow1 + kb);
    __syncthreads();
    *(int4*)&As[r0][gd*8]    = a0;
    *(int4*)&Bs[r0][gd*8]    = b0;
    *(int4*)&Bs[r0+64][gd*8] = b1;
    __syncthreads();
    short8 af[2], bf[4];
    #pragma unroll
    for (int m=0;m<2;m++){
      int R = 32*wr + 16*m + lrow;
      af[m] = *(const short8*)&As[R][(lhi^((R>>1)&3))<<3];
    }
    #pragma unroll
    for (int n=0;n<4;n++){
      int R = 64*wc + 16*n + lrow;
      bf[n] = *(const short8*)&Bs[R][(lhi^((R>>1)&3))<<3];
    }
    #pragma unroll
    for (int m=0;m<2;m++)
      #pragma unroll
      for (int n=0;n<4;n++)
        acc[m][n] = __builtin_amdgcn_mfma_f32_16x16x32_bf16(af[m], bf[n], acc[m][n], 0,0,0);
  }
#endif
  #pragma unroll
  for (int m=0;m<2;m++)
    #pragma unroll
    for (int n=0;n<4;n++)
      #pragma unroll
      for (int q=0;q<4;q++){
        int row = mb + 32*wr + 16*m + 4*lhi + q;
        int col = nb + 64*wc + 16*n + lrow;
        Cout[(size_t)row*N + col] = acc[m][n][q] + bias[col];
      }
}

// ---------------- flash attention v8 (proven): dbuf + split-k + O^T PV + exp2 ----------------
__global__ __launch_bounds__(512, 4) void k_attn8(const unsigned short* __restrict__ Q,
                                                  const unsigned short* __restrict__ K,
                                                  const unsigned short* __restrict__ VT,
                                                  unsigned short* __restrict__ Y){
  __shared__ __align__(16) char smem[65536];
  typedef unsigned short (*tile_t)[2][4096];
  tile_t Ks = (tile_t)smem;
  tile_t Vs = (tile_t)(smem + 32768);
  float (*cmb)[64][35] = (float (*)[64][35])smem;

  int bh = blockIdx.y; int b = bh >> 4, h = bh & 15;
  int s_ = blockIdx.x;
  int tid = threadIdx.x;
  int wave = tid>>6, lane = tid&63;
  int wpair = wave & 3, p = wave >> 2;
  int lrow = lane&15, lhi = lane>>4;
  const unsigned short* Qh = Q + (((size_t)b*Hh + h)*Tt)*HDd;
  const unsigned short* Kh = K + (((size_t)b*Hh + h)*Tt)*HDd;
  const unsigned short* Vh = VT + (((size_t)b*Hh + h)*HDd)*Tt;
  int qL0 = 64*s_ + 16*wpair;
  int qH0 = 1984 - 64*s_ + 16*wpair;
  short8 qfL0 = *(const short8*)&Qh[(size_t)(qL0+lrow)*HDd + 8*lhi];
  short8 qfL1 = *(const short8*)&Qh[(size_t)(qL0+lrow)*HDd + 32 + 8*lhi];
  short8 qfH0 = *(const short8*)&Qh[(size_t)(qH0+lrow)*HDd + 8*lhi];
  short8 qfH1 = *(const short8*)&Qh[(size_t)(qH0+lrow)*HDd + 32 + 8*lhi];
  f32x4 oL[4] = {}, oH[4] = {};             // O^T: [jp] -> O[q=lrow][d=16jp+4lhi+r]
  float lsL = 0.0f, lsH = 0.0f;
  int rowL = qL0 + lrow, rowH = qH0 + lrow;
  int ntL = s_ + 1;
  int NTH = 32 - s_;
  int NI  = (NTH + 1) >> 1;

  int kr = tid >> 3, kc = tid & 7;
  int o_ = tid * 16;
  int ksrc = kr*HDd + ((kc ^ (kr&7)) << 3);
  int vsrc = kr*Tt  + ((kc ^ (kr&7)) << 3);

#ifdef USE_GLL
#define STAGE2(bufi, base_) do { \
    __builtin_amdgcn_global_load_lds((const AS_GLOBAL void*)(Kh + (size_t)(base_)*64*HDd + ksrc), \
        (AS_LDS void*)((AS_LDS char*)&Ks[bufi][0][0] + o_), 16, 0, 0); \
    __builtin_amdgcn_global_load_lds((const AS_GLOBAL void*)(Vh + (size_t)(base_)*64 + vsrc), \
        (AS_LDS void*)((AS_LDS char*)&Vs[bufi][0][0] + o_), 16, 0, 0); \
    if ((base_)+1 < NTH){ \
      __builtin_amdgcn_global_load_lds((const AS_GLOBAL void*)(Kh + (size_t)((base_)+1)*64*HDd + ksrc), \
          (AS_LDS void*)((AS_LDS char*)&Ks[bufi][1][0] + o_), 16, 0, 0); \
      __builtin_amdgcn_global_load_lds((const AS_GLOBAL void*)(Vh + (size_t)((base_)+1)*64 + vsrc), \
          (AS_LDS void*)((AS_LDS char*)&Vs[bufi][1][0] + o_), 16, 0, 0); \
    } \
  } while(0)
#else
#define STAGE2(bufi, base_) do { \
    int4 a_ = *(const int4*)(Kh + (size_t)(base_)*64*HDd + ksrc); \
    int4 c_ = *(const int4*)(Vh + (size_t)(base_)*64 + vsrc); \
    *(int4*)((char*)&Ks[bufi][0][0] + o_) = a_; \
    *(int4*)((char*)&Vs[bufi][0][0] + o_) = c_; \
    if ((base_)+1 < NTH){ \
      int4 b_ = *(const int4*)(Kh + (size_t)((base_)+1)*64*HDd + ksrc); \
      int4 d_ = *(const int4*)(Vh + (size_t)((base_)+1)*64 + vsrc); \
      *(int4*)((char*)&Ks[bufi][1][0] + o_) = b_; \
      *(int4*)((char*)&Vs[bufi][1][0] + o_) = d_; \
    } \
  } while(0)
#endif

  STAGE2(0, 0);
  int buf = 0;
  for (int i = 0; i < NI; i++){
    __syncthreads();
    if (i+1 < NI) STAGE2(buf^1, 2*(i+1));
    int kt = 2*i + p;
    if (kt < NTH){
      int k0 = kt*64;
      bool doL = (kt < ntL);
      const unsigned short* Kbase = &Ks[buf][p][0];
      const unsigned short* Vbase = &Vs[buf][p][0];
      f32x4 sL[4] = {}, sH[4] = {};
      __builtin_amdgcn_s_setprio(1);
      #pragma unroll
      for (int j=0;j<4;j++){
        int krow = 16*j + lrow;
        #pragma unroll
        for (int ks=0;ks<2;ks++){
          int dgrp = (4*ks + lhi) ^ (krow&7);
          short8 kf = *(const short8*)&Kbase[krow*64 + dgrp*8];
          sH[j] = __builtin_amdgcn_mfma_f32_16x16x32_bf16(kf, ks ? qfH1 : qfH0, sH[j], 0,0,0);
          if (doL) sL[j] = __builtin_amdgcn_mfma_f32_16x16x32_bf16(kf, ks ? qfL1 : qfL0, sL[j], 0,0,0);
        }
      }
      __builtin_amdgcn_s_setprio(0);
      short4v paH[4], paL[4];
      {
        bool diagH = (k0 + 63 >= qH0);
        #pragma unroll
        for (int j=0;j<4;j++){
          int kbase = k0 + 16*j + 4*lhi;
          float p0 = exp2fast(sH[j][0]);
          float p1 = exp2fast(sH[j][1]);
          float p2 = exp2fast(sH[j][2]);
          float p3 = exp2fast(sH[j][3]);
          if (diagH){
            if (kbase + 0 > rowH) p0 = 0.0f;
            if (kbase + 1 > rowH) p1 = 0.0f;
            if (kbase + 2 > rowH) p2 = 0.0f;
            if (kbase + 3 > rowH) p3 = 0.0f;
          }
          lsH += (p0 + p1) + (p2 + p3);
          union { unsigned int u[2]; short4v v; } pk;
          pk.u[0] = cvtpk_bf16(p0, p1);
          pk.u[1] = cvtpk_bf16(p2, p3);
          paH[j] = pk.v;
        }
      }
      if (doL){
        bool diagL = (k0 + 63 >= qL0);
        #pragma unroll
        for (int j=0;j<4;j++){
          int kbase = k0 + 16*j + 4*lhi;
          float p0 = exp2fast(sL[j][0]);
          float p1 = exp2fast(sL[j][1]);
          float p2 = exp2fast(sL[j][2]);
          float p3 = exp2fast(sL[j][3]);
          if (diagL){
            if (kbase + 0 > rowL) p0 = 0.0f;
            if (kbase + 1 > rowL) p1 = 0.0f;
            if (kbase + 2 > rowL) p2 = 0.0f;
            if (kbase + 3 > rowL) p3 = 0.0f;
          }
          lsL += (p0 + p1) + (p2 + p3);
          union { unsigned int u[2]; short4v v; } pk;
          pk.u[0] = cvtpk_bf16(p0, p1);
          pk.u[1] = cvtpk_bf16(p2, p3);
          paL[j] = pk.v;
        }
      }
      __builtin_amdgcn_s_setprio(1);
      #pragma unroll
      for (int jp=0;jp<4;jp++){
        int vrow = 16*jp + lrow;
        #pragma unroll
        for (int j=0;j<4;j++){
          int byte_in_row = ((((2*j + (lhi>>1)) ^ (vrow&7)) << 4) | ((lhi&1) << 3));
          short4v vf = *(const short4v*)((const char*)&Vbase[vrow*64] + byte_in_row);
          oH[jp] = mfma16(vf, paH[j], oH[jp]);       // A=V^T frag, B=P^T frag
          if (doL) oL[jp] = mfma16(vf, paL[j], oL[jp]);
        }
      }
      __builtin_amdgcn_s_setprio(0);
    }
    buf ^= 1;
  }

  __syncthreads();
  if (p == 1){
    float* c = &cmb[wpair][lane][0];
    #pragma unroll
    for (int jp=0;jp<4;jp++)
      #pragma unroll
      for (int r=0;r<4;r++){
        c[4*jp+r]    = oL[jp][r];
        c[16+4*jp+r] = oH[jp][r];
      }
    c[32] = lsL; c[33] = lsH;
  }
  __syncthreads();
  if (p == 0){
    const float* c = &cmb[wpair][lane][0];
    #pragma unroll
    for (int jp=0;jp<4;jp++)
      #pragma unroll
      for (int r=0;r<4;r++){
        oL[jp][r] += c[4*jp+r];
        oH[jp][r] += c[16+4*jp+r];
      }
    lsL += c[32]; lsH += c[33];
    lsL += __shfl_xor(lsL, 16); lsL += __shfl_xor(lsL, 32);
    lsH += __shfl_xor(lsH, 16); lsH += __shfl_xor(lsH, 32);
    float invL = 1.0f / lsL, invH = 1.0f / lsH;
    size_t rbL = ((size_t)b*Tt + qL0 + lrow)*Cc + h*HDd + 4*lhi;
    size_t rbH = ((size_t)b*Tt + qH0 + lrow)*Cc + h*HDd + 4*lhi;
    #pragma unroll
    for (int jp=0;jp<4;jp++){
      unsigned int l0 = cvtpk_bf16(oL[jp][0]*invL, oL[jp][1]*invL);
      unsigned int l1 = cvtpk_bf16(oL[jp][2]*invL, oL[jp][3]*invL);
      unsigned int h0_ = cvtpk_bf16(oH[jp][0]*invH, oH[jp][1]*invH);
      unsigned int h1_ = cvtpk_bf16(oH[jp][2]*invH, oH[jp][3]*invH);
      *(unsigned long long*)&Y[rbL + 16*jp] = (unsigned long long)l0 | ((unsigned long long)l1<<32);
      *(unsigned long long*)&Y[rbH + 16*jp] = (unsigned long long)h0_ | ((unsigned long long)h1_<<32);
    }
  }
#undef STAGE2
}

extern "C" void kernel_launch(void* const* d_in, const int* in_sizes, int n_in,
                              void* d_out, int out_size, void* d_ws, size_t ws_size,
                              hipStream_t stream){
  const float* x     = (const float*)d_in[0];
  const float* cum   = (const float*)d_in[1];
  const int*   tok   = (const int*)d_in[3];
  const float* Wqkv  = (const float*)d_in[4];
  const float* bqkv  = (const float*)d_in[5];
  const float* Wproj = (const float*)d_in[6];
  const float* bproj = (const float*)d_in[7];

  char* ws = (char*)d_ws;
  size_t off = 0;
  auto alloc = [&](size_t bytes)->void*{
    void* p = ws + off; off += (bytes + 255) & ~(size_t)255; return p;
  };
  unsigned short* wqkvT = (unsigned short*)alloc((size_t)3072*1024*2);
  unsigned short* wprojT= (unsigned short*)alloc((size_t)1024*1024*2);
  unsigned short* xb    = (unsigned short*)alloc((size_t)4096*1024*2); // reused as Y
  unsigned short* Qb    = (unsigned short*)alloc((size_t)Bb*Hh*Tt*HDd*2);
  unsigned short* Kb    = (unsigned short*)alloc((size_t)Bb*Hh*Tt*HDd*2);
  unsigned short* VTb   = (unsigned short*)alloc((size_t)Bb*Hh*Tt*HDd*2);
  float* cs_t           = (float*)alloc((size_t)Bb*Tt*64*4);
  unsigned short* Y     = xb; // alias: xb dead after QKV GEMM

  k_f2b<<<dim3(4096*1024/8/256), dim3(256), 0, stream>>>(x, xb, 4096*1024);
  k_transpose_f2b<<<dim3(3072/32, 1024/32, 2), dim3(32,8), 0, stream>>>(Wqkv, Wproj, wqkvT, wprojT);
  k_scan<<<dim3(Bb), dim3(1024), 0, stream>>>(tok, cs_t);
  k_gemmQKV<<<dim3(3072/128, 4096/128), dim3(256), 0, stream>>>(xb, wqkvT, bqkv, cs_t, cum, Qb, Kb, VTb);
  k_attn8<<<dim3(16, Bb*Hh), dim3(512), 0, stream>>>(Qb, Kb, VTb, Y);
  k_gemm64<<<dim3(1024/128, 4096/64), dim3(256), 0, stream>>>(Y, wprojT, bproj, (float*)d_out, 4096, 1024, 1024);
}